// Round 8
// baseline (168.838 us; speedup 1.0000x reference)
//
#include <hip/hip_runtime.h>

#define CH 32     // steps per chunk (N = 4194304 divisible by 32)
#define CPB 64    // chunks per block = one wave
#define F4C 24    // float4s per chunk (32 steps * 3 floats = 96 = 24 float4)
#define TILE (CPB * F4C)   // 1536 float4s = 24 KB per array

// Reference step: s <- sigmoid(10*((s + u) - 0.5)) — identical ops/order to the
// PASSED R2/R7 kernels (absmax 0.0078 vs 0.1575 threshold). Every op is
// monotone non-decreasing in s, so the chunk map is monotone: if trajectories
// from lo and 1 land on identical floats, any start in [lo,1] lands there too.
// lo=0 for chunks>=1 (incoming is a sigmoid output); lo=-1 for chunk 0
// (net0 in (-1,1]) — chunk 0 is ALSO recomputed exactly from net0 in p2.
__device__ __forceinline__ float sig10(float s, float u) {
    float t = (s + u) - 0.5f;
    float a = 10.0f * t;
    float e = __expf(-a);
    return 1.0f / (1.0f + e);   // IEEE divide: monotone
}

__device__ __forceinline__ void step3(float& s0, float& s1, float& s2,
                                      float u0, float u1, float u2) {
    s0 = sig10(s0, u0); s1 = sig10(s1, u1); s2 = sig10(s2, u2);
}

// XOR-swizzle: float4 #F of a wave-tile lives at su[F ^ ((F/24)&7)].
// Writer (coalesced load order, F = ld*64+lane) and reader (chunk order,
// F = lane*24+j, F/24 == lane) use the same involution => bijective.
// Read banks: low3(F') = (j%8)^(lane%8) -> 4-way b128 (1.58x, cheap).
__device__ __forceinline__ int swz(int F) { return F ^ ((F / F4C) & 7); }

// ---- Phase 1: bracket each chunk (coalesced LDS-staged u); emit candidate
// incoming state for chunk c+1, per-chunk flag, per-block flag-OR.
__global__ void p1_bracket(
    const float* __restrict__ update, float* __restrict__ state_in,
    int* __restrict__ flags, int* __restrict__ blockflags, int C, int N) {
  __shared__ float4 su[TILE];
  const int lane = threadIdx.x;          // 64 threads = 1 wave
  const int blk  = blockIdx.x;
  const int c    = blk * CPB + lane;
  const bool blockFull = ((size_t)(blk + 1) * (CPB * CH) <= (size_t)N);
  int flag = 0;
  float a0 = 0.f, a1 = 0.f, a2 = 0.f;

  if (blockFull) {
    // coalesced stage: lane loads float4s ld*64+lane (contiguous per instr)
    const float4* up4 = (const float4*)update + (size_t)blk * TILE;
    float4 raw[F4C];
#pragma unroll
    for (int ld = 0; ld < F4C; ++ld) raw[ld] = up4[ld * CPB + lane];
#pragma unroll
    for (int ld = 0; ld < F4C; ++ld) su[swz(ld * CPB + lane)] = raw[ld];
    __syncthreads();

    const float lo = (c == 0) ? -1.0f : 0.0f;
    a0 = a1 = a2 = lo;
    float b0 = 1.f, b1 = 1.f, b2 = 1.f;
    bool bdone = false;
    const int base = lane * F4C;
#pragma unroll
    for (int g = 0; g < 8; ++g) {
      const float4 A  = su[swz(base + 3 * g + 0)];
      const float4 B  = su[swz(base + 3 * g + 1)];
      const float4 Cv = su[swz(base + 3 * g + 2)];
      step3(a0, a1, a2, A.x, A.y, A.z);
      step3(a0, a1, a2, A.w, B.x, B.y);
      step3(a0, a1, a2, B.z, B.w, Cv.x);
      step3(a0, a1, a2, Cv.y, Cv.z, Cv.w);
      if (!bdone) {                 // wave-uniform early exit of upper bracket
        step3(b0, b1, b2, A.x, A.y, A.z);
        step3(b0, b1, b2, A.w, B.x, B.y);
        step3(b0, b1, b2, B.z, B.w, Cv.x);
        step3(b0, b1, b2, Cv.y, Cv.z, Cv.w);
        bdone = __all((a0 == b0) && (a1 == b1) && (a2 == b2));
      }
    }
    flag = bdone ? 0 : 1;  // conservative (per-wave); exact repair covers it
  } else if (c < C) {
    // tail (not hit for N=4194304): scalar per-lane
    const float* up = update + (size_t)c * (CH * 3);
    int steps = min(CH, N - c * CH);
    const float lo = (c == 0) ? -1.0f : 0.0f;
    a0 = a1 = a2 = lo;
    float b0 = 1.f, b1 = 1.f, b2 = 1.f;
    for (int i = 0; i < steps; ++i) {
      step3(a0, a1, a2, up[3 * i], up[3 * i + 1], up[3 * i + 2]);
      step3(b0, b1, b2, up[3 * i], up[3 * i + 1], up[3 * i + 2]);
    }
    flag = !((a0 == b0) && (a1 == b1) && (a2 == b2));
  }

  if (c < C) {
    if (c + 1 < C) {
      state_in[(size_t)(c + 1) * 3 + 0] = a0;
      state_in[(size_t)(c + 1) * 3 + 1] = a1;
      state_in[(size_t)(c + 1) * 3 + 2] = a2;
    }
    flags[c] = flag;
  }
  unsigned long long bal = __ballot(flag != 0);   // single wave per block
  if (lane == 0) blockflags[blk] = (bal != 0ull) ? 1 : 0;
}

// ---- Phase 2: resolve chunk 0 exactly from net0; if any block flagged,
// sequentially repair flagged chunks in ascending order (exact; ~never taken).
__global__ void p2_fix(const float* __restrict__ update,
                       const float* __restrict__ net0,
                       float* __restrict__ state_in,
                       const int* __restrict__ flags,
                       const int* __restrict__ blockflags,
                       int C, int N, int NBLK) {
  __shared__ int s_any;
  if (threadIdx.x == 0) s_any = 0;
  __syncthreads();
  int bad = 0;
  for (int i = threadIdx.x; i < NBLK; i += blockDim.x) bad |= blockflags[i];
  if (bad) atomicOr(&s_any, 1);
  __syncthreads();
  if (threadIdx.x != 0) return;
  const int any = s_any;

  float s0 = net0[0], s1 = net0[1], s2 = net0[2];
  state_in[0] = s0; state_in[1] = s1; state_in[2] = s2;
  {  // chunk 0: always exact
    const float* up = update;
    int steps = min(CH, N);
    for (int i = 0; i < steps; ++i)
      step3(s0, s1, s2, up[3 * i], up[3 * i + 1], up[3 * i + 2]);
    if (C > 1) { state_in[3] = s0; state_in[4] = s1; state_in[5] = s2; }
  }
  if (!any) return;
  for (int blk = 0; blk < NBLK; ++blk) {
    if (!blockflags[blk]) continue;
    int cc0 = blk * CPB; if (cc0 == 0) cc0 = 1;   // chunk 0 already exact
    int cc1 = min(blk * CPB + CPB, C);
    for (int cc = cc0; cc < cc1; ++cc) {
      if (!flags[cc]) continue;
      float t0 = state_in[(size_t)cc * 3 + 0];
      float t1 = state_in[(size_t)cc * 3 + 1];
      float t2 = state_in[(size_t)cc * 3 + 2];
      const float* up = update + (size_t)cc * (CH * 3);
      int steps = min(CH, N - cc * CH);
      for (int i = 0; i < steps; ++i)
        step3(t0, t1, t2, up[3 * i], up[3 * i + 1], up[3 * i + 2]);
      if (cc + 1 < C) {
        state_in[(size_t)(cc + 1) * 3 + 0] = t0;
        state_in[(size_t)(cc + 1) * 3 + 1] = t1;
        state_in[(size_t)(cc + 1) * 3 + 2] = t2;
      }
    }
  }
}

// ---- Phase 3: replay each chunk from its exact incoming state; u and x
// staged coalesced via swizzled LDS tiles; out staged (reusing the u-tile)
// for fully-coalesced 256B/instr stores.
__global__ void p3_emit(
    const float* __restrict__ x, const float* __restrict__ update,
    const float* __restrict__ state_in, float* __restrict__ out, int C, int N) {
  __shared__ float4 su[TILE];
  __shared__ float4 sx[TILE];
  const int lane = threadIdx.x;          // 64 threads = 1 wave
  const int blk  = blockIdx.x;
  const int c    = blk * CPB + lane;
  const bool blockFull = ((size_t)(blk + 1) * (CPB * CH) <= (size_t)N);

  if (blockFull) {
    const float4* up4 = (const float4*)update + (size_t)blk * TILE;
    const float4* xp4 = (const float4*)x      + (size_t)blk * TILE;
    float4 ru[F4C], rx[F4C];
#pragma unroll
    for (int ld = 0; ld < F4C; ++ld) ru[ld] = up4[ld * CPB + lane];
#pragma unroll
    for (int ld = 0; ld < F4C; ++ld) rx[ld] = xp4[ld * CPB + lane];
#pragma unroll
    for (int ld = 0; ld < F4C; ++ld) su[swz(ld * CPB + lane)] = ru[ld];
#pragma unroll
    for (int ld = 0; ld < F4C; ++ld) sx[swz(ld * CPB + lane)] = rx[ld];
    __syncthreads();

    float s0 = state_in[(size_t)c * 3 + 0];
    float s1 = state_in[(size_t)c * 3 + 1];
    float s2 = state_in[(size_t)c * 3 + 2];
    float obuf[CH];
    const int base = lane * F4C;
#pragma unroll
    for (int g = 0; g < 8; ++g) {
      const float4 UA = su[swz(base + 3 * g + 0)];
      const float4 UB = su[swz(base + 3 * g + 1)];
      const float4 UC = su[swz(base + 3 * g + 2)];
      const float4 XA = sx[swz(base + 3 * g + 0)];
      const float4 XB = sx[swz(base + 3 * g + 1)];
      const float4 XC = sx[swz(base + 3 * g + 2)];
      step3(s0, s1, s2, UA.x, UA.y, UA.z);
      obuf[g * 4 + 0] = XA.x * s0 + XA.y * s1 + XA.z * s2;
      step3(s0, s1, s2, UA.w, UB.x, UB.y);
      obuf[g * 4 + 1] = XA.w * s0 + XB.x * s1 + XB.y * s2;
      step3(s0, s1, s2, UB.z, UB.w, UC.x);
      obuf[g * 4 + 2] = XB.z * s0 + XB.w * s1 + XC.x * s2;
      step3(s0, s1, s2, UC.y, UC.z, UC.w);
      obuf[g * 4 + 3] = XC.y * s0 + XC.z * s1 + XC.w * s2;
    }
    __syncthreads();                       // u-tile dead; reuse as out stage
    float* s_o = (float*)su;               // [64][33] stride-33: 2-way banks
#pragma unroll
    for (int i = 0; i < CH; ++i) s_o[lane * 33 + i] = obuf[i];
    __syncthreads();
    float* ob = out + (size_t)blk * (CPB * CH);
#pragma unroll
    for (int k = 0; k < CH; ++k) {
      int f = k * CPB + lane;              // dword index in block's 2048 slab
      int t = f >> 5, idx = f & 31;        // owning chunk, offset
      ob[f] = s_o[t * 33 + idx];           // wave writes 256B contiguous
    }
  } else if (c < C) {
    // tail (not hit for N=4194304)
    float s0 = state_in[(size_t)c * 3 + 0];
    float s1 = state_in[(size_t)c * 3 + 1];
    float s2 = state_in[(size_t)c * 3 + 2];
    const float* up = update + (size_t)c * (CH * 3);
    const float* xp = x + (size_t)c * (CH * 3);
    float* op = out + (size_t)c * CH;
    int steps = min(CH, N - c * CH);
    for (int i = 0; i < steps; ++i) {
      step3(s0, s1, s2, up[3 * i], up[3 * i + 1], up[3 * i + 2]);
      op[i] = xp[3 * i] * s0 + xp[3 * i + 1] * s1 + xp[3 * i + 2] * s2;
    }
  }
}

extern "C" void kernel_launch(void* const* d_in, const int* in_sizes, int n_in,
                              void* d_out, int out_size, void* d_ws, size_t ws_size,
                              hipStream_t stream) {
    const float* x      = (const float*)d_in[0];   // [N,1,3]
    const float* update = (const float*)d_in[1];   // [N,3,1]
    const float* net0   = (const float*)d_in[2];   // [3,1]
    float* out = (float*)d_out;                    // [N,1]
    int N = out_size;
    int C = (N + CH - 1) / CH;
    int nblk = (C + CPB - 1) / CPB;                // 2048 blocks of 1 wave

    // workspace: state_in (C*3 f32) | flags (C int) | blockflags (nblk int)
    float* state_in = (float*)d_ws;
    int* flags = (int*)((char*)d_ws + (size_t)C * 3 * sizeof(float));
    int* blockflags = flags + C;

    hipLaunchKernelGGL(p1_bracket, dim3(nblk), dim3(CPB), 0, stream,
                       update, state_in, flags, blockflags, C, N);
    hipLaunchKernelGGL(p2_fix, dim3(1), dim3(256), 0, stream,
                       update, net0, state_in, flags, blockflags, C, N, nblk);
    hipLaunchKernelGGL(p3_emit, dim3(nblk), dim3(CPB), 0, stream,
                       x, update, state_in, out, C, N);
}

// Round 9
// 145.149 us; speedup vs baseline: 1.1632x; 1.1632x over previous
//
#include <hip/hip_runtime.h>

#define CH 32     // bracket chunk = 32 steps (exactness: P(no merge) ~ 3e-7)
#define HCH 16    // p3 half-chunk = 16 steps (parallelism)
#define TPB 256

// Reference step: s <- sigmoid(10*((s + u) - 0.5)) — identical ops/order to
// the PASSED R2/R7/R8 kernels (absmax 0.0078 vs 0.1575 threshold). Monotone
// non-decreasing in s => bracket squeeze is exact: if trajectories from lo
// and 1 land on identical floats at step k, ANY start in [lo,1] does too.
// lo=0 for chunks>=1 (incoming is a sigmoid output); lo=-1 for chunk 0
// (net0 in (-1,1]).
__device__ __forceinline__ float sig10(float s, float u) {
    float t = (s + u) - 0.5f;
    float a = 10.0f * t;
    float e = __expf(-a);
    return 1.0f / (1.0f + e);   // IEEE divide: monotone
}

__device__ __forceinline__ void step3(float& s0, float& s1, float& s2,
                                      float u0, float u1, float u2) {
    s0 = sig10(s0, u0); s1 = sig10(s1, u1); s2 = sig10(s2, u2);
}

// ---- Phase 1: bracket each chunk. Emits:
//  state_in[c+1] : end-state (exact iff flags[c]==0)
//  state_mid[c]  : step-16 state (exact iff midflags[c]==0)
//  flags[c]      : per-lane "brackets not merged by step 32"
//  midflags[c]   : per-lane "brackets not merged by step 16"
//  blockflags[b] : OR of flags (repair trigger only)
__global__ void __launch_bounds__(TPB, 3) p1_bracket(
    const float* __restrict__ update, float* __restrict__ state_in,
    float* __restrict__ state_mid, int* __restrict__ flags,
    int* __restrict__ midflags, int* __restrict__ blockflags, int C, int N) {
  __shared__ int s_w[TPB / 64];
  const int tid = threadIdx.x;
  if (tid < TPB / 64) s_w[tid] = 0;
  __syncthreads();
  const int c = blockIdx.x * TPB + tid;
  const bool have = (c < C);
  const bool full = have && ((size_t)(c + 1) * CH <= (size_t)N);
  int flag = 0, mflag = 0;
  float a0 = 0.f, a1 = 0.f, a2 = 0.f;
  float m0 = 0.f, m1 = 0.f, m2 = 0.f;
  if (full) {
    const float4* up4 = (const float4*)(update + (size_t)c * (CH * 3));
    float4 u[24];
#pragma unroll
    for (int g = 0; g < 24; ++g) u[g] = up4[g];   // batch-issue all 24 loads
    const float lo = (c == 0) ? -1.0f : 0.0f;
    a0 = a1 = a2 = lo;
    float b0 = 1.f, b1 = 1.f, b2 = 1.f;
    bool lanem = false;   // this lane's brackets have merged (sticky)
    bool bdone = false;   // wave-uniform: all lanes merged
#pragma unroll
    for (int g = 0; g < 8; ++g) {
      const float4 A = u[3 * g], B = u[3 * g + 1], Cv = u[3 * g + 2];
      step3(a0, a1, a2, A.x, A.y, A.z);
      step3(a0, a1, a2, A.w, B.x, B.y);
      step3(a0, a1, a2, B.z, B.w, Cv.x);
      step3(a0, a1, a2, Cv.y, Cv.z, Cv.w);
      if (!bdone) {                 // wave-uniform early exit of upper bracket
        step3(b0, b1, b2, A.x, A.y, A.z);
        step3(b0, b1, b2, A.w, B.x, B.y);
        step3(b0, b1, b2, B.z, B.w, Cv.x);
        step3(b0, b1, b2, Cv.y, Cv.z, Cv.w);
        bool mg = (a0 == b0) && (a1 == b1) && (a2 == b2);
        lanem = lanem || mg;        // equal floats stay equal => sticky valid
        bdone = __all(mg);
      }
      if (g == 3) {                 // after 16 steps: record mid-state
        m0 = a0; m1 = a1; m2 = a2;
        mflag = lanem ? 0 : 1;
      }
    }
    flag = lanem ? 0 : 1;
  } else if (have) {
    // tail chunk (not hit for N=4194304): scalar exact path
    const float* up = update + (size_t)c * (CH * 3);
    int steps = N - c * CH;
    const float lo = (c == 0) ? -1.0f : 0.0f;
    a0 = a1 = a2 = lo;
    float b0 = 1.f, b1 = 1.f, b2 = 1.f;
    bool lanem = false;
    for (int i = 0; i < steps; ++i) {
      step3(a0, a1, a2, up[3 * i], up[3 * i + 1], up[3 * i + 2]);
      step3(b0, b1, b2, up[3 * i], up[3 * i + 1], up[3 * i + 2]);
      lanem = lanem || ((a0 == b0) && (a1 == b1) && (a2 == b2));
      if (i == HCH - 1) { m0 = a0; m1 = a1; m2 = a2; mflag = lanem ? 0 : 1; }
    }
    flag = lanem ? 0 : 1;
  }
  if (have) {
    if (c + 1 < C) {
      state_in[(size_t)(c + 1) * 3 + 0] = a0;
      state_in[(size_t)(c + 1) * 3 + 1] = a1;
      state_in[(size_t)(c + 1) * 3 + 2] = a2;
    }
    state_mid[(size_t)c * 3 + 0] = m0;
    state_mid[(size_t)c * 3 + 1] = m1;
    state_mid[(size_t)c * 3 + 2] = m2;
    flags[c] = flag;
    midflags[c] = mflag;
  }
  unsigned long long bal = __ballot(flag != 0);
  if ((tid & 63) == 0) s_w[tid >> 6] = (bal != 0ull) ? 1 : 0;
  __syncthreads();
  if (tid == 0) {
    int bf = 0;
#pragma unroll
    for (int w = 0; w < TPB / 64; ++w) bf |= s_w[w];
    blockflags[blockIdx.x] = bf;
  }
}

// ---- Phase 2: flag scan; only if some chunk failed to collapse (p ~ 1e-8),
// serially repair flagged chunks in ascending order (exact; chunk 0 from net0).
__global__ void p2_fix(const float* __restrict__ update,
                       const float* __restrict__ net0,
                       float* __restrict__ state_in,
                       const int* __restrict__ flags,
                       const int* __restrict__ blockflags,
                       int C, int N, int NBLK) {
  __shared__ int s_any;
  if (threadIdx.x == 0) s_any = 0;
  __syncthreads();
  int bad = 0;
  for (int i = threadIdx.x; i < NBLK; i += blockDim.x) bad |= blockflags[i];
  if (bad) atomicOr(&s_any, 1);
  __syncthreads();
  if (threadIdx.x != 0) return;
  if (!s_any) return;                          // common path: nothing to do
  for (int cc = 0; cc < C; ++cc) {
    if (!flags[cc]) continue;
    float t0, t1, t2;
    if (cc == 0) { t0 = net0[0]; t1 = net0[1]; t2 = net0[2]; }
    else {
      t0 = state_in[(size_t)cc * 3 + 0];       // exact: predecessors repaired
      t1 = state_in[(size_t)cc * 3 + 1];
      t2 = state_in[(size_t)cc * 3 + 2];
    }
    const float* up = update + (size_t)cc * (CH * 3);
    int steps = min(CH, N - cc * CH);
    for (int i = 0; i < steps; ++i)
      step3(t0, t1, t2, up[3 * i], up[3 * i + 1], up[3 * i + 2]);
    if (cc + 1 < C) {
      state_in[(size_t)(cc + 1) * 3 + 0] = t0;
      state_in[(size_t)(cc + 1) * 3 + 1] = t1;
      state_in[(size_t)(cc + 1) * 3 + 2] = t2;
    }
  }
}

// ---- Phase 3: TWO threads per chunk (16 steps each) for 2x wave count.
// Even thread starts from state_in[c] (net0 for c==0); odd from state_mid[c]
// (or replays the first half itself when midflags[c] — rare, exact).
__global__ void __launch_bounds__(TPB, 3) p3_emit(
    const float* __restrict__ x, const float* __restrict__ update,
    const float* __restrict__ net0, const float* __restrict__ state_in,
    const float* __restrict__ state_mid, const int* __restrict__ midflags,
    float* __restrict__ out, int C, int N) {
  __shared__ float s_o[TPB * 17];     // 16 outs/thread, stride-17: 2-way banks
  const int tid = threadIdx.x;
  const int tt = blockIdx.x * TPB + tid;
  const int c = tt >> 1, h = tt & 1;
  const bool fullBlock = ((size_t)(blockIdx.x + 1) * (TPB * HCH) <= (size_t)N);
  if (fullBlock) {
    const float4* up4 = (const float4*)(update + (size_t)c * (CH * 3)) + h * 12;
    const float4* xp4 = (const float4*)(x + (size_t)c * (CH * 3)) + h * 12;
    float4 u[12], xv[12];
#pragma unroll
    for (int g = 0; g < 12; ++g) u[g] = up4[g];    // batch: 24 loads in flight
#pragma unroll
    for (int g = 0; g < 12; ++g) xv[g] = xp4[g];
    float s0, s1, s2;
    if (h == 0) {
      if (c == 0) { s0 = net0[0]; s1 = net0[1]; s2 = net0[2]; }
      else {
        s0 = state_in[(size_t)c * 3 + 0];
        s1 = state_in[(size_t)c * 3 + 1];
        s2 = state_in[(size_t)c * 3 + 2];
      }
    } else if (midflags[c] == 0) {
      s0 = state_mid[(size_t)c * 3 + 0];
      s1 = state_mid[(size_t)c * 3 + 1];
      s2 = state_mid[(size_t)c * 3 + 2];
    } else {                          // rare (~1e-3): replay first half, exact
      if (c == 0) { s0 = net0[0]; s1 = net0[1]; s2 = net0[2]; }
      else {
        s0 = state_in[(size_t)c * 3 + 0];
        s1 = state_in[(size_t)c * 3 + 1];
        s2 = state_in[(size_t)c * 3 + 2];
      }
      const float* up = update + (size_t)c * (CH * 3);
      for (int i = 0; i < HCH; ++i)
        step3(s0, s1, s2, up[3 * i], up[3 * i + 1], up[3 * i + 2]);
    }
    float obuf[HCH];
#pragma unroll
    for (int g = 0; g < 4; ++g) {
      const float4 UA = u[3 * g], UB = u[3 * g + 1], UC = u[3 * g + 2];
      const float4 XA = xv[3 * g], XB = xv[3 * g + 1], XC = xv[3 * g + 2];
      step3(s0, s1, s2, UA.x, UA.y, UA.z);
      obuf[g * 4 + 0] = XA.x * s0 + XA.y * s1 + XA.z * s2;
      step3(s0, s1, s2, UA.w, UB.x, UB.y);
      obuf[g * 4 + 1] = XA.w * s0 + XB.x * s1 + XB.y * s2;
      step3(s0, s1, s2, UB.z, UB.w, UC.x);
      obuf[g * 4 + 2] = XB.z * s0 + XB.w * s1 + XC.x * s2;
      step3(s0, s1, s2, UC.y, UC.z, UC.w);
      obuf[g * 4 + 3] = XC.y * s0 + XC.z * s1 + XC.w * s2;
    }
#pragma unroll
    for (int i = 0; i < HCH; ++i) s_o[tid * 17 + i] = obuf[i];
    __syncthreads();
    float* ob = out + (size_t)blockIdx.x * (TPB * HCH);
#pragma unroll
    for (int k = 0; k < HCH; ++k) {
      int f = k * TPB + tid;          // dword index in block's 4096-float slab
      ob[f] = s_o[(f >> 4) * 17 + (f & 15)];   // 1 KB/instr coalesced store
    }
  } else if (c < C) {
    // tail (not hit for N=4194304): scalar exact path
    int steps = min(CH, N - c * CH);
    int i0 = h * HCH, i1 = min(steps, (h + 1) * HCH);
    if (i0 >= i1) return;
    float s0, s1, s2;
    bool replay = false;
    if (h == 0 || midflags[c] != 0) {
      if (c == 0) { s0 = net0[0]; s1 = net0[1]; s2 = net0[2]; }
      else {
        s0 = state_in[(size_t)c * 3 + 0];
        s1 = state_in[(size_t)c * 3 + 1];
        s2 = state_in[(size_t)c * 3 + 2];
      }
      replay = (h == 1);
    } else {
      s0 = state_mid[(size_t)c * 3 + 0];
      s1 = state_mid[(size_t)c * 3 + 1];
      s2 = state_mid[(size_t)c * 3 + 2];
    }
    const float* up = update + (size_t)c * (CH * 3);
    const float* xp = x + (size_t)c * (CH * 3);
    float* op = out + (size_t)c * CH;
    if (replay)
      for (int i = 0; i < i0; ++i)
        step3(s0, s1, s2, up[3 * i], up[3 * i + 1], up[3 * i + 2]);
    for (int i = i0; i < i1; ++i) {
      step3(s0, s1, s2, up[3 * i], up[3 * i + 1], up[3 * i + 2]);
      op[i] = xp[3 * i] * s0 + xp[3 * i + 1] * s1 + xp[3 * i + 2] * s2;
    }
  }
}

extern "C" void kernel_launch(void* const* d_in, const int* in_sizes, int n_in,
                              void* d_out, int out_size, void* d_ws, size_t ws_size,
                              hipStream_t stream) {
    const float* x      = (const float*)d_in[0];   // [N,1,3]
    const float* update = (const float*)d_in[1];   // [N,3,1]
    const float* net0   = (const float*)d_in[2];   // [3,1]
    float* out = (float*)d_out;                    // [N,1]
    int N = out_size;
    int C = (N + CH - 1) / CH;
    int nblk1 = (C + TPB - 1) / TPB;               // p1: 512 blocks
    int nblk3 = (2 * C + TPB - 1) / TPB;           // p3: 1024 blocks

    // ws: state_in C*3 f32 | state_mid C*3 f32 | flags C | midflags C | blockflags
    char* w = (char*)d_ws;
    float* state_in  = (float*)w;                         w += (size_t)C * 3 * 4;
    float* state_mid = (float*)w;                         w += (size_t)C * 3 * 4;
    int* flags       = (int*)w;                           w += (size_t)C * 4;
    int* midflags    = (int*)w;                           w += (size_t)C * 4;
    int* blockflags  = (int*)w;

    hipLaunchKernelGGL(p1_bracket, dim3(nblk1), dim3(TPB), 0, stream,
                       update, state_in, state_mid, flags, midflags,
                       blockflags, C, N);
    hipLaunchKernelGGL(p2_fix, dim3(1), dim3(TPB), 0, stream,
                       update, net0, state_in, flags, blockflags, C, N, nblk1);
    hipLaunchKernelGGL(p3_emit, dim3(nblk3), dim3(TPB), 0, stream,
                       x, update, net0, state_in, state_mid, midflags,
                       out, C, N);
}